// Round 3
// baseline (389.944 us; speedup 1.0000x reference)
//
#include <hip/hip_runtime.h>
#include <stdint.h>

// RLeaky SNN scan: b=16, t=128, n=512, f=32, beta=0.9, thresh=1.0.
// Established (R0-R2 forensics): outputs are fp32 (268 MB total, spikes then
// mems). Input storage dtypes (fp32 vs bf16) are detected at runtime per
// block: packed-bf16 data has sane exponents in every dword's LOW halfword;
// fp32 data has random mantissa bits there. Detection is deterministic and
// wave-uniform -> graph-safe.
// Layout: each lane owns output features g0=2j, g0+1 of one (b,n) row.
// 16 lanes/row, 4 rows/wave, block=256 -> 16 rows/block, 512 blocks.
// State (mem, spk) persistent in registers for all 128 steps. Recurrent
// matvec via __ballot spike masks + ordered f=0..31 fma accumulation,
// bit-exact vs np.einsum's sequential fp32 sum (products exact, spk in {0,1}).

#define T_STEPS   128
#define N_DIM     512
#define F_DIM     32
#define N_ROWS    8192                    // b*n
#define STEP_ELE  (N_DIM * F_DIM)         // 16384 elements per t-step
#define OUT_HALF  (16 * 128 * 512 * 32)   // fp32 elements per output tensor

__device__ __forceinline__ float bf16h_to_f32(uint32_t h) {
    return __uint_as_float(h << 16);
}

template<bool XF32>
__device__ __forceinline__ float2 load_x2(const char* p) {
    if (XF32) {
        return *(const float2*)p;
    } else {
        const uint32_t d = *(const uint32_t*)p;
        return make_float2(__uint_as_float(d << 16),
                           __uint_as_float(d & 0xFFFF0000u));
    }
}

template<bool XF32>
__device__ __forceinline__ void scan_loop(const char* __restrict__ xbase,
                                          float* __restrict__ sp,
                                          float* __restrict__ mp,
                                          const float* __restrict__ Wg0,
                                          const float* __restrict__ Wg1,
                                          float bias0, float bias1, int rshift)
{
#pragma clang fp contract(off)
    const ptrdiff_t XS = (ptrdiff_t)STEP_ELE * (XF32 ? 4 : 2);  // bytes per t

    // Depth-2 prefetch of x.
    float2 xa = load_x2<XF32>(xbase);
    float2 xb = load_x2<XF32>(xbase + XS);
    const char* xpp = xbase + 2 * XS;

    float mem0 = 0.0f, mem1 = 0.0f, spk0 = 0.0f, spk1 = 0.0f;

#pragma unroll 2
    for (int t = 0; t < T_STEPS; ++t) {
        const float2 xv = xa;
        xa = xb;
        xb = load_x2<XF32>(xpp);
        xpp += (t < T_STEPS - 3) ? XS : 0;   // uniform; stays in-bounds

        // Row spike masks: bit q of me = spk[2q], of mo = spk[2q+1].
        const unsigned long long be = __ballot(spk0 != 0.0f);
        const unsigned long long bo = __ballot(spk1 != 0.0f);
        const uint32_t me = (uint32_t)(be >> rshift) & 0xFFFFu;
        const uint32_t mo = (uint32_t)(bo >> rshift) & 0xFFFFu;

        // Ordered f=0..31 accumulation, matching np's sequential fp32 sum.
        float s0 = 0.0f, s1 = 0.0f;
#pragma unroll
        for (int q = 0; q < 16; ++q) {
            const float fe = (float)((me >> q) & 1u);
            const float fo = (float)((mo >> q) & 1u);
            s0 = __builtin_fmaf(fe, Wg0[2 * q],     s0);
            s0 = __builtin_fmaf(fo, Wg0[2 * q + 1], s0);
            s1 = __builtin_fmaf(fe, Wg1[2 * q],     s1);
            s1 = __builtin_fmaf(fo, Wg1[2 * q + 1], s1);
        }
        const float rec0 = s0 + bias0;
        const float rec1 = s1 + bias1;

        // mem = ((beta*mem + x) + rec) - spk*1.0, each op rounded.
        float t0 = 0.9f * mem0; t0 = t0 + xv.x; t0 = t0 + rec0; mem0 = t0 - spk0;
        float t1 = 0.9f * mem1; t1 = t1 + xv.y; t1 = t1 + rec1; mem1 = t1 - spk1;

        spk0 = (mem0 - 1.0f > 0.0f) ? 1.0f : 0.0f;
        spk1 = (mem1 - 1.0f > 0.0f) ? 1.0f : 0.0f;

        *(float2*)sp = make_float2(spk0, spk1);
        *(float2*)mp = make_float2(mem0, mem1);
        sp += STEP_ELE;
        mp += STEP_ELE;
    }
}

__global__ __launch_bounds__(256, 2)
void snn_rleaky_kernel(const void* __restrict__ x,
                       const void* __restrict__ W,
                       const void* __restrict__ b_lin,
                       float* __restrict__ out)
{
    const int tid  = threadIdx.x;

    // ---- runtime dtype detection (deterministic, identical in all blocks) --
    __shared__ int s_insane[3];
    if (tid < 3) s_insane[tid] = 0;
    __syncthreads();
    {
        const uint32_t dx = ((const uint32_t*)x)[tid];     // 256 samples
        if (((dx >> 7) & 0xFFu) > 0x82u) s_insane[0] = 1;  // |bf16| >= ~16
        const uint32_t dw = ((const uint32_t*)W)[tid];     // 256 samples
        if (((dw >> 7) & 0xFFu) > 0x7Du) s_insane[1] = 1;  // |bf16| >= ~0.25
        if (tid < 16) {
            const uint32_t db = ((const uint32_t*)b_lin)[tid];
            if (((db >> 7) & 0xFFu) > 0x7Du) s_insane[2] = 1;
        }
    }
    __syncthreads();
    const bool x_f32 = (s_insane[0] != 0);
    const bool w_f32 = (s_insane[1] != 0);
    const bool b_f32 = (s_insane[2] != 0);

    // ---- per-lane setup ----------------------------------------------------
    const int j    = tid & 15;                  // lane within row
    const int rrow = tid >> 4;                  // row within block: 0..15
    const int row  = blockIdx.x * 16 + rrow;    // global row: 0..8191
    const int b_i  = row >> 9;
    const int n_i  = row & 511;
    const int g0   = j << 1;                    // output features g0, g0+1
    const int rshift = (rrow & 3) << 4;         // row's 16-bit ballot slice

    float Wg0[32], Wg1[32];
    if (w_f32) {
        const float* Wf = (const float*)W;
#pragma unroll
        for (int f = 0; f < 32; ++f) {
            Wg0[f] = Wf[g0 * 32 + f];
            Wg1[f] = Wf[(g0 + 1) * 32 + f];
        }
    } else {
        const uint16_t* Wh = (const uint16_t*)W;
#pragma unroll
        for (int f = 0; f < 32; ++f) {
            Wg0[f] = bf16h_to_f32(Wh[g0 * 32 + f]);
            Wg1[f] = bf16h_to_f32(Wh[(g0 + 1) * 32 + f]);
        }
    }
    float bias0, bias1;
    if (b_f32) {
        bias0 = ((const float*)b_lin)[g0];
        bias1 = ((const float*)b_lin)[g0 + 1];
    } else {
        bias0 = bf16h_to_f32(((const uint16_t*)b_lin)[g0]);
        bias1 = bf16h_to_f32(((const uint16_t*)b_lin)[g0 + 1]);
    }

    // Base element offset at t=0 for this lane's 2 features ((b,t,n,f) layout).
    const size_t base = ((size_t)b_i * T_STEPS * N_DIM + n_i) * F_DIM + g0;
    float* sp = out + base;                      // spikes (fp32)
    float* mp = out + (size_t)OUT_HALF + base;   // mems   (fp32)
    const char* xbase = (const char*)x + base * (x_f32 ? 4 : 2);

    if (x_f32) scan_loop<true >(xbase, sp, mp, Wg0, Wg1, bias0, bias1, rshift);
    else       scan_loop<false>(xbase, sp, mp, Wg0, Wg1, bias0, bias1, rshift);
}

extern "C" void kernel_launch(void* const* d_in, const int* in_sizes, int n_in,
                              void* d_out, int out_size, void* d_ws, size_t ws_size,
                              hipStream_t stream) {
    const void* x  = d_in[0];
    const void* W  = d_in[1];
    const void* bl = d_in[2];
    float* out = (float*)d_out;

    dim3 grid(N_ROWS / 16);   // 512 blocks, 16 rows each
    dim3 block(256);
    hipLaunchKernelGGL(snn_rleaky_kernel, grid, block, 0, stream, x, W, bl, out);
}